// Round 5
// baseline (338.700 us; speedup 1.0000x reference)
//
#include <hip/hip_runtime.h>
#include <hip/hip_bf16.h>

#define NN 100000      // nodes
#define NE 3200000     // edges
#define NF 256         // features
// support stored feature-blocked: chunk c holds feats [c*128,(c+1)*128)
// as bf16, layout [chunk][node][128]; 256 B per node per chunk.

typedef __attribute__((ext_vector_type(8))) __bf16 bf16x8;
typedef __attribute__((ext_vector_type(4))) float  f32x4;
typedef __attribute__((ext_vector_type(2))) float  f32x2;

static __device__ __forceinline__ float lo2f(unsigned int d) {
    union { unsigned int i; float f; } c; c.i = d << 16; return c.f;
}
static __device__ __forceinline__ float hi2f(unsigned int d) {
    union { unsigned int i; float f; } c; c.i = d & 0xffff0000u; return c.f;
}

// ---- W -> per-lane MFMA B-fragments (bf16), same k-map as A-build below ----
__global__ __launch_bounds__(256) void prep_w(const float* __restrict__ w,
                                              __bf16* __restrict__ wfrag) {
    const int t = blockIdx.x * 256 + threadIdx.x;   // 8192 total
    const int lane = t & 63;
    const int nf   = (t >> 6) & 15;
    const int ks   = t >> 10;
    const int col  = nf * 16 + (lane & 15);
    const int k0   = ks * 32 + (lane >> 4) * 8;
    bf16x8 v;
#pragma unroll
    for (int j = 0; j < 8; ++j) v[j] = (__bf16)w[(k0 + j) * NF + col];
    reinterpret_cast<bf16x8*>(wfrag)[t] = v;
}

// ---- support = x @ W via mfma_f32_16x16x32_bf16; 5 waves x 16 rows/block ----
// C written into the feature-blocked layout.
__global__ __launch_bounds__(320) void gemm_mfma(const float* __restrict__ x,
                                                 const __bf16* __restrict__ wfrag,
                                                 __bf16* __restrict__ support) {
    const int wv   = threadIdx.x >> 6;
    const int lane = threadIdx.x & 63;
    const int row0 = blockIdx.x * 80 + wv * 16;

    f32x4 acc[16];
#pragma unroll
    for (int nf = 0; nf < 16; ++nf) acc[nf] = (f32x4){0.f, 0.f, 0.f, 0.f};

    const float* xp = x + (size_t)(row0 + (lane & 15)) * NF + ((lane >> 4) << 3);
    const bf16x8* wf = reinterpret_cast<const bf16x8*>(wfrag);

#pragma unroll
    for (int ks = 0; ks < 8; ++ks) {
        const f32x4 a0 = __builtin_nontemporal_load(
            reinterpret_cast<const f32x4*>(xp + ks * 32));
        const f32x4 a1 = __builtin_nontemporal_load(
            reinterpret_cast<const f32x4*>(xp + ks * 32 + 4));
        bf16x8 af;
        af[0] = (__bf16)a0.x; af[1] = (__bf16)a0.y;
        af[2] = (__bf16)a0.z; af[3] = (__bf16)a0.w;
        af[4] = (__bf16)a1.x; af[5] = (__bf16)a1.y;
        af[6] = (__bf16)a1.z; af[7] = (__bf16)a1.w;
#pragma unroll
        for (int nf = 0; nf < 16; ++nf) {
            const bf16x8 bfr = wf[(ks * 16 + nf) * 64 + lane];
            acc[nf] = __builtin_amdgcn_mfma_f32_16x16x32_bf16(af, bfr, acc[nf], 0, 0, 0);
        }
    }

    // C/D: col = lane&15, row = (lane>>4)*4 + reg  (m89-verified)
    const int crow = row0 + ((lane >> 4) << 2);
    const int ccol = lane & 15;
#pragma unroll
    for (int nf = 0; nf < 16; ++nf) {
        const int col   = nf * 16 + ccol;
        const int chunk = col >> 7;          // 0 or 1
        const int within = col & 127;
#pragma unroll
        for (int r = 0; r < 4; ++r)
            support[(size_t)chunk * NN * 128 + (size_t)(crow + r) * 128 + within] =
                (__bf16)acc[nf][r];
    }
}

// ---- CSR row pointers from sorted edge_row (int32) ----
__global__ void build_rowptr(const int* __restrict__ erow,
                             int* __restrict__ rowptr) {
    int e = blockIdx.x * blockDim.x + threadIdx.x;
    if (e >= NE) return;
    int r    = erow[e];
    int prev = (e == 0) ? -1 : erow[e - 1];
    for (int q = prev + 1; q <= r; ++q) rowptr[q] = e;
    if (e == NE - 1) {
        for (int q = r + 1; q <= NN; ++q) rowptr[q] = NE;
    }
}

// ---- spmm over one 128-feature chunk: one wave per row, lane owns 2 feats ----
// Gather is 4 B/lane, 256 B contiguous per wave per edge.
__global__ __launch_bounds__(256) void spmm_chunk(const unsigned int* __restrict__ spc,
                                                  const int* __restrict__ rowptr,
                                                  const int* __restrict__ ecol,
                                                  const float* __restrict__ eval,
                                                  const float* __restrict__ bias_c,
                                                  float* __restrict__ out_c) {
    const int wave = threadIdx.x >> 6;
    const int lane = threadIdx.x & 63;
    const int row  = blockIdx.x * 4 + wave;

    const int s = rowptr[row];
    const int e = rowptr[row + 1];

    const char* base = reinterpret_cast<const char*>(spc) + lane * 4;

    float a0 = 0.f, a1 = 0.f;
#pragma unroll 4
    for (int i = s; i < e; ++i) {
        const int   c = ecol[i];
        const float v = eval[i];
        const unsigned int g =
            *reinterpret_cast<const unsigned int*>(base + ((size_t)c << 8)); // 256 B/node
        a0 = fmaf(v, lo2f(g), a0);
        a1 = fmaf(v, hi2f(g), a1);
    }

    const f32x2 b = *reinterpret_cast<const f32x2*>(bias_c + lane * 2);
    f32x2 o; o.x = a0 + b.x; o.y = a1 + b.y;
    __builtin_nontemporal_store(
        o, reinterpret_cast<f32x2*>(out_c + (size_t)row * NF + lane * 2));
}

extern "C" void kernel_launch(void* const* d_in, const int* in_sizes, int n_in,
                              void* d_out, int out_size, void* d_ws, size_t ws_size,
                              hipStream_t stream) {
    const float* x    = (const float*)d_in[0];
    const int*   erow = (const int*)d_in[1];
    const int*   ecol = (const int*)d_in[2];
    const float* eval = (const float*)d_in[3];
    const float* w    = (const float*)d_in[4];
    const float* bias = (const float*)d_in[5];
    float*       out  = (float*)d_out;

    __bf16* support = (__bf16*)d_ws;                                   // 51,200,000 B
    int*    rowptr  = (int*)((char*)d_ws + 51200000);                  // 400,004 B
    __bf16* wfrag   = (__bf16*)((char*)d_ws + 51600016);               // 131,072 B

    prep_w<<<32, 256, 0, stream>>>(w, wfrag);
    build_rowptr<<<(NE + 255) / 256, 256, 0, stream>>>(erow, rowptr);
    gemm_mfma<<<NN / 80, 320, 0, stream>>>(x, wfrag, support);

    // Two sequential passes (stream-serialized) -> 25.6 MB working set each.
    const unsigned int* sp32 = reinterpret_cast<const unsigned int*>(support);
    spmm_chunk<<<NN / 4, 256, 0, stream>>>(sp32, rowptr, ecol, eval,
                                           bias, out);
    spmm_chunk<<<NN / 4, 256, 0, stream>>>(sp32 + (size_t)NN * 64, rowptr, ecol, eval,
                                           bias + 128, out + 128);
}

// Round 6
// 249.249 us; speedup vs baseline: 1.3589x; 1.3589x over previous
//
#include <hip/hip_runtime.h>
#include <hip/hip_bf16.h>

#define NN 100000      // nodes
#define NE 3200000     // edges
#define NF 256         // features

typedef __attribute__((ext_vector_type(8))) __bf16 bf16x8;
typedef __attribute__((ext_vector_type(4))) float  f32x4;

static __device__ __forceinline__ float bf2f(unsigned short u) {
    union { unsigned int i; float f; } c; c.i = ((unsigned int)u) << 16; return c.f;
}

// ---- W -> per-lane MFMA B-fragments (bf16), same k-map as A-build below ----
__global__ __launch_bounds__(256) void prep_w(const float* __restrict__ w,
                                              __bf16* __restrict__ wfrag) {
    const int t = blockIdx.x * 256 + threadIdx.x;   // 8192 total
    const int lane = t & 63;
    const int nf   = (t >> 6) & 15;
    const int ks   = t >> 10;
    const int col  = nf * 16 + (lane & 15);
    const int k0   = ks * 32 + (lane >> 4) * 8;
    bf16x8 v;
#pragma unroll
    for (int j = 0; j < 8; ++j) v[j] = (__bf16)w[(k0 + j) * NF + col];
    reinterpret_cast<bf16x8*>(wfrag)[t] = v;
}

// ---- support = x @ W via mfma_f32_16x16x32_bf16; 5 waves x 16 rows/block ----
__global__ __launch_bounds__(320) void gemm_mfma(const float* __restrict__ x,
                                                 const __bf16* __restrict__ wfrag,
                                                 __bf16* __restrict__ support) {
    const int wv   = threadIdx.x >> 6;
    const int lane = threadIdx.x & 63;
    const int row0 = blockIdx.x * 80 + wv * 16;

    f32x4 acc[16];
#pragma unroll
    for (int nf = 0; nf < 16; ++nf) acc[nf] = (f32x4){0.f, 0.f, 0.f, 0.f};

    const float* xp = x + (size_t)(row0 + (lane & 15)) * NF + ((lane >> 4) << 3);
    const bf16x8* wf = reinterpret_cast<const bf16x8*>(wfrag);

#pragma unroll
    for (int ks = 0; ks < 8; ++ks) {
        const f32x4 a0 = __builtin_nontemporal_load(
            reinterpret_cast<const f32x4*>(xp + ks * 32));
        const f32x4 a1 = __builtin_nontemporal_load(
            reinterpret_cast<const f32x4*>(xp + ks * 32 + 4));
        bf16x8 af;
        af[0] = (__bf16)a0.x; af[1] = (__bf16)a0.y;
        af[2] = (__bf16)a0.z; af[3] = (__bf16)a0.w;
        af[4] = (__bf16)a1.x; af[5] = (__bf16)a1.y;
        af[6] = (__bf16)a1.z; af[7] = (__bf16)a1.w;
#pragma unroll
        for (int nf = 0; nf < 16; ++nf) {
            const bf16x8 bfr = wf[(ks * 16 + nf) * 64 + lane];
            acc[nf] = __builtin_amdgcn_mfma_f32_16x16x32_bf16(af, bfr, acc[nf], 0, 0, 0);
        }
    }

    // C/D: col = lane&15, row = (lane>>4)*4 + reg  (m89-verified)
    const int crow = row0 + ((lane >> 4) << 2);
    const int ccol = lane & 15;
#pragma unroll
    for (int nf = 0; nf < 16; ++nf) {
#pragma unroll
        for (int r = 0; r < 4; ++r)
            support[(size_t)(crow + r) * NF + nf * 16 + ccol] = (__bf16)acc[nf][r];
    }
}

// ---- CSR row pointers from sorted edge_row (int32) ----
__global__ void build_rowptr(const int* __restrict__ erow,
                             int* __restrict__ rowptr) {
    int e = blockIdx.x * blockDim.x + threadIdx.x;
    if (e >= NE) return;
    int r    = erow[e];
    int prev = (e == 0) ? -1 : erow[e - 1];
    for (int q = prev + 1; q <= r; ++q) rowptr[q] = e;
    if (e == NE - 1) {
        for (int q = r + 1; q <= NN; ++q) rowptr[q] = NE;
    }
}

// ---- quantize: bf16 support row -> i8 (per-row absmax scale), IN PLACE ----
// One wave per node. Reads 512 B bf16 row, writes packed i8 into the row's
// first 256 B (the wave-wide read completes before the store issues).
__global__ __launch_bounds__(256) void quantize(unsigned short* __restrict__ srow,
                                                float* __restrict__ scales) {
    const int node = blockIdx.x * 4 + (threadIdx.x >> 6);
    const int lane = threadIdx.x & 63;
    unsigned short* rp = srow + (size_t)node * NF;

    const ushort4 s4 = reinterpret_cast<const ushort4*>(rp)[lane];   // 8 B = 4 bf16
    const float f0 = bf2f(s4.x), f1 = bf2f(s4.y), f2 = bf2f(s4.z), f3 = bf2f(s4.w);

    float m = fmaxf(fmaxf(fabsf(f0), fabsf(f1)), fmaxf(fabsf(f2), fabsf(f3)));
#pragma unroll
    for (int w = 1; w < 64; w <<= 1) m = fmaxf(m, __shfl_xor(m, w, 64));

    const float iscale = 127.0f / fmaxf(m, 1e-30f);
    const int q0 = (int)rintf(f0 * iscale);
    const int q1 = (int)rintf(f1 * iscale);
    const int q2 = (int)rintf(f2 * iscale);
    const int q3 = (int)rintf(f3 * iscale);
    const unsigned int pk = (q0 & 0xff) | ((q1 & 0xff) << 8) |
                            ((q2 & 0xff) << 16) | ((unsigned)(q3 & 0xff) << 24);
    reinterpret_cast<unsigned int*>(rp)[lane] = pk;    // bytes lane*4 .. lane*4+3
    if (lane == 0) scales[node] = m * (1.0f / 127.0f);
}

// ---- spmm (i8 table): one wave per row; 4 B/lane gather = 256 B/edge ----
// Table row n lives at tab + n*512 (first 256 B of the old bf16 row).
__global__ __launch_bounds__(256) void spmm_i8(const char* __restrict__ tab,
                                               const int* __restrict__ rowptr,
                                               const int* __restrict__ ecol,
                                               const float* __restrict__ eval,
                                               const float* __restrict__ scales,
                                               const float* __restrict__ bias,
                                               float* __restrict__ out) {
    const int wave = threadIdx.x >> 6;
    const int lane = threadIdx.x & 63;
    const int row  = blockIdx.x * 4 + wave;

    const int s = rowptr[row];
    const int e = rowptr[row + 1];

    const char* base = tab + lane * 4;
    float a0 = 0.f, a1 = 0.f, a2 = 0.f, a3 = 0.f;

#pragma unroll 4
    for (int i = s; i < e; ++i) {
        const int   c  = ecol[i];                       // wave-uniform
        const float v  = eval[i] * scales[c];           // scales: 400 KB, L2-hot
        const unsigned int g =
            *reinterpret_cast<const unsigned int*>(base + ((size_t)c << 9));
        a0 = fmaf(v, (float)(int)(signed char)(g      ), a0);
        a1 = fmaf(v, (float)(int)(signed char)(g >> 8 ), a1);
        a2 = fmaf(v, (float)(int)(signed char)(g >> 16), a2);
        a3 = fmaf(v, (float)(int)(signed char)(g >> 24), a3);
    }

    const f32x4 b4 = *reinterpret_cast<const f32x4*>(bias + lane * 4);
    f32x4 o;
    o.x = a0 + b4.x; o.y = a1 + b4.y; o.z = a2 + b4.z; o.w = a3 + b4.w;
    __builtin_nontemporal_store(
        o, reinterpret_cast<f32x4*>(out + (size_t)row * NF + lane * 4));
}

extern "C" void kernel_launch(void* const* d_in, const int* in_sizes, int n_in,
                              void* d_out, int out_size, void* d_ws, size_t ws_size,
                              hipStream_t stream) {
    const float* x    = (const float*)d_in[0];
    const int*   erow = (const int*)d_in[1];
    const int*   ecol = (const int*)d_in[2];
    const float* eval = (const float*)d_in[3];
    const float* w    = (const float*)d_in[4];
    const float* bias = (const float*)d_in[5];
    float*       out  = (float*)d_out;

    __bf16* support = (__bf16*)d_ws;                                   // 51,200,000 B
    int*    rowptr  = (int*)((char*)d_ws + 51200000);                  //    400,004 B
    __bf16* wfrag   = (__bf16*)((char*)d_ws + 51600016);               //    131,072 B
    float*  scales  = (float*)((char*)d_ws + 51731088);                //    400,000 B

    prep_w<<<32, 256, 0, stream>>>(w, wfrag);
    build_rowptr<<<(NE + 255) / 256, 256, 0, stream>>>(erow, rowptr);
    gemm_mfma<<<NN / 80, 320, 0, stream>>>(x, wfrag, support);
    quantize<<<NN / 4, 256, 0, stream>>>(
        reinterpret_cast<unsigned short*>(support), scales);
    spmm_i8<<<NN / 4, 256, 0, stream>>>(
        reinterpret_cast<const char*>(support), rowptr, ecol, eval, scales, bias, out);
}

// Round 7
// 232.500 us; speedup vs baseline: 1.4568x; 1.0720x over previous
//
#include <hip/hip_runtime.h>
#include <hip/hip_bf16.h>

#define NN 100000      // nodes
#define NE 3200000     // edges
#define NF 256         // features

typedef __attribute__((ext_vector_type(8))) __bf16 bf16x8;
typedef __attribute__((ext_vector_type(4))) float  f32x4;

static __device__ __forceinline__ float bf2f(unsigned short u) {
    union { unsigned int i; float f; } c; c.i = ((unsigned int)u) << 16; return c.f;
}

// ---- W -> per-lane MFMA B-fragments (bf16), same k-map as A-frag below ----
__global__ __launch_bounds__(256) void prep_w(const float* __restrict__ w,
                                              __bf16* __restrict__ wfrag) {
    const int t = blockIdx.x * 256 + threadIdx.x;   // 8192 total
    const int lane = t & 63;
    const int nf   = (t >> 6) & 15;
    const int ks   = t >> 10;
    const int col  = nf * 16 + (lane & 15);
    const int k0   = ks * 32 + (lane >> 4) * 8;
    bf16x8 v;
#pragma unroll
    for (int j = 0; j < 8; ++j) v[j] = (__bf16)w[(k0 + j) * NF + col];
    reinterpret_cast<bf16x8*>(wfrag)[t] = v;
}

// ---- support = x @ W via mfma_f32_16x16x32_bf16, LDS-staged x ----
// Block: 320 threads (5 waves) x 16 rows = 80 rows. Per k-phase (BK=32):
// coalesced 80x32 f32 stage -> bf16 LDS tile (row stride 72 bf16 = 144 B,
// 4-bank step => 2-way conflict, free), reg-staged prefetch of next slice
// overlaps the 16 MFMAs. Fragment/C-write mapping identical to round 6.
__global__ __launch_bounds__(320) void gemm_lds(const float* __restrict__ x,
                                                const __bf16* __restrict__ wfrag,
                                                __bf16* __restrict__ support) {
    __shared__ __align__(16) __bf16 As[80 * 72];   // 11,520 B

    const int t    = threadIdx.x;
    const int wv   = t >> 6;
    const int lane = t & 63;
    const int row0 = blockIdx.x * 80;

    f32x4 acc[16];
#pragma unroll
    for (int nf = 0; nf < 16; ++nf) acc[nf] = (f32x4){0.f, 0.f, 0.f, 0.f};

    // staging role: thread t covers row (t>>2), k-offset (t&3)*8 (8 floats)
    const int   srow = t >> 2;
    const int   sj   = (t & 3) * 8;
    const float* xp  = x + (size_t)(row0 + srow) * NF + sj;
    char* const  wr  = reinterpret_cast<char*>(As) + srow * 144 + sj * 2;

    // A-frag read: row = wv*16 + (lane&15), k-offset = (lane>>4)*8
    const char* const rd =
        reinterpret_cast<const char*>(As) + (wv * 16 + (lane & 15)) * 144 + ((lane >> 4) << 4);

    const bf16x8* wf = reinterpret_cast<const bf16x8*>(wfrag);

    f32x4 s0 = __builtin_nontemporal_load(reinterpret_cast<const f32x4*>(xp));
    f32x4 s1 = __builtin_nontemporal_load(reinterpret_cast<const f32x4*>(xp + 4));

    for (int ks = 0; ks < 8; ++ks) {
        bf16x8 sb;
        sb[0] = (__bf16)s0.x; sb[1] = (__bf16)s0.y;
        sb[2] = (__bf16)s0.z; sb[3] = (__bf16)s0.w;
        sb[4] = (__bf16)s1.x; sb[5] = (__bf16)s1.y;
        sb[6] = (__bf16)s1.z; sb[7] = (__bf16)s1.w;
        *reinterpret_cast<bf16x8*>(wr) = sb;       // ds_write_b128
        __syncthreads();

        if (ks < 7) {                              // prefetch next slice -> regs
            s0 = __builtin_nontemporal_load(
                reinterpret_cast<const f32x4*>(xp + (ks + 1) * 32));
            s1 = __builtin_nontemporal_load(
                reinterpret_cast<const f32x4*>(xp + (ks + 1) * 32 + 4));
        }

        const bf16x8 af = *reinterpret_cast<const bf16x8*>(rd);  // ds_read_b128
#pragma unroll
        for (int nf = 0; nf < 16; ++nf) {
            const bf16x8 bfr = wf[(ks * 16 + nf) * 64 + lane];
            acc[nf] = __builtin_amdgcn_mfma_f32_16x16x32_bf16(af, bfr, acc[nf], 0, 0, 0);
        }
        __syncthreads();
    }

    // C/D: col = lane&15, row = (lane>>4)*4 + reg  (m89-verified) — unchanged
    const int crow = row0 + wv * 16 + ((lane >> 4) << 2);
    const int ccol = lane & 15;
#pragma unroll
    for (int nf = 0; nf < 16; ++nf) {
#pragma unroll
        for (int r = 0; r < 4; ++r)
            support[(size_t)(crow + r) * NF + nf * 16 + ccol] = (__bf16)acc[nf][r];
    }
}

// ---- CSR row pointers from sorted edge_row (int32) ----
__global__ void build_rowptr(const int* __restrict__ erow,
                             int* __restrict__ rowptr) {
    int e = blockIdx.x * blockDim.x + threadIdx.x;
    if (e >= NE) return;
    int r    = erow[e];
    int prev = (e == 0) ? -1 : erow[e - 1];
    for (int q = prev + 1; q <= r; ++q) rowptr[q] = e;
    if (e == NE - 1) {
        for (int q = r + 1; q <= NN; ++q) rowptr[q] = NE;
    }
}

// ---- quantize: bf16 support row -> i8 (per-row absmax scale), IN PLACE ----
__global__ __launch_bounds__(256) void quantize(unsigned short* __restrict__ srow,
                                                float* __restrict__ scales) {
    const int node = blockIdx.x * 4 + (threadIdx.x >> 6);
    const int lane = threadIdx.x & 63;
    unsigned short* rp = srow + (size_t)node * NF;

    const ushort4 s4 = reinterpret_cast<const ushort4*>(rp)[lane];   // 8 B = 4 bf16
    const float f0 = bf2f(s4.x), f1 = bf2f(s4.y), f2 = bf2f(s4.z), f3 = bf2f(s4.w);

    float m = fmaxf(fmaxf(fabsf(f0), fabsf(f1)), fmaxf(fabsf(f2), fabsf(f3)));
#pragma unroll
    for (int w = 1; w < 64; w <<= 1) m = fmaxf(m, __shfl_xor(m, w, 64));

    const float iscale = 127.0f / fmaxf(m, 1e-30f);
    const int q0 = (int)rintf(f0 * iscale);
    const int q1 = (int)rintf(f1 * iscale);
    const int q2 = (int)rintf(f2 * iscale);
    const int q3 = (int)rintf(f3 * iscale);
    const unsigned int pk = (q0 & 0xff) | ((q1 & 0xff) << 8) |
                            ((q2 & 0xff) << 16) | ((unsigned)(q3 & 0xff) << 24);
    reinterpret_cast<unsigned int*>(rp)[lane] = pk;
    if (lane == 0) scales[node] = m * (1.0f / 127.0f);
}

// ---- spmm (i8 table): one wave per row; 4 B/lane gather = 256 B/edge ----
__global__ __launch_bounds__(256) void spmm_i8(const char* __restrict__ tab,
                                               const int* __restrict__ rowptr,
                                               const int* __restrict__ ecol,
                                               const float* __restrict__ eval,
                                               const float* __restrict__ scales,
                                               const float* __restrict__ bias,
                                               float* __restrict__ out) {
    const int wave = threadIdx.x >> 6;
    const int lane = threadIdx.x & 63;
    const int row  = blockIdx.x * 4 + wave;

    const int s = rowptr[row];
    const int e = rowptr[row + 1];

    const char* base = tab + lane * 4;
    float a0 = 0.f, a1 = 0.f, a2 = 0.f, a3 = 0.f;

#pragma unroll 4
    for (int i = s; i < e; ++i) {
        const int   c  = ecol[i];                       // wave-uniform
        const float v  = eval[i] * scales[c];           // scales: 400 KB, L2-hot
        const unsigned int g =
            *reinterpret_cast<const unsigned int*>(base + ((size_t)c << 9));
        a0 = fmaf(v, (float)(int)(signed char)(g      ), a0);
        a1 = fmaf(v, (float)(int)(signed char)(g >> 8 ), a1);
        a2 = fmaf(v, (float)(int)(signed char)(g >> 16), a2);
        a3 = fmaf(v, (float)(int)(signed char)(g >> 24), a3);
    }

    const f32x4 b4 = *reinterpret_cast<const f32x4*>(bias + lane * 4);
    f32x4 o;
    o.x = a0 + b4.x; o.y = a1 + b4.y; o.z = a2 + b4.z; o.w = a3 + b4.w;
    __builtin_nontemporal_store(
        o, reinterpret_cast<f32x4*>(out + (size_t)row * NF + lane * 4));
}

extern "C" void kernel_launch(void* const* d_in, const int* in_sizes, int n_in,
                              void* d_out, int out_size, void* d_ws, size_t ws_size,
                              hipStream_t stream) {
    const float* x    = (const float*)d_in[0];
    const int*   erow = (const int*)d_in[1];
    const int*   ecol = (const int*)d_in[2];
    const float* eval = (const float*)d_in[3];
    const float* w    = (const float*)d_in[4];
    const float* bias = (const float*)d_in[5];
    float*       out  = (float*)d_out;

    __bf16* support = (__bf16*)d_ws;                                   // 51,200,000 B
    int*    rowptr  = (int*)((char*)d_ws + 51200000);                  //    400,004 B
    __bf16* wfrag   = (__bf16*)((char*)d_ws + 51600016);               //    131,072 B
    float*  scales  = (float*)((char*)d_ws + 51731088);                //    400,000 B

    prep_w<<<32, 256, 0, stream>>>(w, wfrag);
    build_rowptr<<<(NE + 255) / 256, 256, 0, stream>>>(erow, rowptr);
    gemm_lds<<<NN / 80, 320, 0, stream>>>(x, wfrag, support);
    quantize<<<NN / 4, 256, 0, stream>>>(
        reinterpret_cast<unsigned short*>(support), scales);
    spmm_i8<<<NN / 4, 256, 0, stream>>>(
        reinterpret_cast<const char*>(support), rowptr, ecol, eval, scales, bias, out);
}

// Round 8
// 210.860 us; speedup vs baseline: 1.6063x; 1.1026x over previous
//
#include <hip/hip_runtime.h>
#include <hip/hip_bf16.h>

#define NN 100000      // nodes
#define NE 3200000     // edges
#define NF 256         // features

typedef __attribute__((ext_vector_type(8))) __bf16 bf16x8;
typedef __attribute__((ext_vector_type(4))) float  f32x4;

static __device__ __forceinline__ float bf2f(unsigned short u) {
    union { unsigned int i; float f; } c; c.i = ((unsigned int)u) << 16; return c.f;
}

// Table layout (per node, 256 B): byte p holds feature feat(p) = (p&15)*16 + (p>>4)
// (16x16 transpose). Gemm lane (ccol) packs its 16 features (nf=0..15) into
// bytes [ccol*16, ccol*16+16) contiguously; spmm lane l's 4 bytes at 4l..4l+3
// are features (l&3)*64 + 16b + (l>>2), b=0..3.

// ---- prep: W -> per-lane MFMA B-fragments (bf16) + permuted bias ----
__global__ __launch_bounds__(256) void prep_w(const float* __restrict__ w,
                                              __bf16* __restrict__ wfrag,
                                              const float* __restrict__ bias,
                                              float* __restrict__ bias_p) {
    if (blockIdx.x == 32) {          // permuted bias: bias_p[4l+b] = bias[F(l,b)]
        const int t = threadIdx.x;   // 0..255
        const int l = t >> 2, b = t & 3;
        bias_p[t] = bias[(l & 3) * 64 + 16 * b + (l >> 2)];
        return;
    }
    const int t = blockIdx.x * 256 + threadIdx.x;   // 8192 total
    const int lane = t & 63;
    const int nf   = (t >> 6) & 15;
    const int ks   = t >> 10;
    const int col  = nf * 16 + (lane & 15);
    const int k0   = ks * 32 + (lane >> 4) * 8;
    bf16x8 v;
#pragma unroll
    for (int j = 0; j < 8; ++j) v[j] = (__bf16)w[(k0 + j) * NF + col];
    reinterpret_cast<bf16x8*>(wfrag)[t] = v;
}

// ---- fused GEMM + i8 quantize: support-row = (x @ W) quantized in epilogue ----
// Block: 320 threads (5 waves) x 16 rows = 80 rows; LDS-staged x (BK=32).
__global__ __launch_bounds__(320) void gemm_q(const float* __restrict__ x,
                                              const __bf16* __restrict__ wfrag,
                                              unsigned char* __restrict__ tab,
                                              float* __restrict__ scales) {
    __shared__ __align__(16) __bf16 As[80 * 72];   // row stride 144 B

    const int t    = threadIdx.x;
    const int wv   = t >> 6;
    const int lane = t & 63;
    const int row0 = blockIdx.x * 80;

    f32x4 acc[16];
#pragma unroll
    for (int nf = 0; nf < 16; ++nf) acc[nf] = (f32x4){0.f, 0.f, 0.f, 0.f};

    // staging: thread t covers row (t>>2), k-offset (t&3)*8 (8 floats)
    const int   srow = t >> 2;
    const int   sj   = (t & 3) * 8;
    const float* xp  = x + (size_t)(row0 + srow) * NF + sj;
    char* const  wr  = reinterpret_cast<char*>(As) + srow * 144 + sj * 2;

    // A-frag read: row = wv*16 + (lane&15), k-offset = (lane>>4)*8
    const char* const rd =
        reinterpret_cast<const char*>(As) + (wv * 16 + (lane & 15)) * 144 + ((lane >> 4) << 4);

    const bf16x8* wf = reinterpret_cast<const bf16x8*>(wfrag);

    f32x4 s0 = __builtin_nontemporal_load(reinterpret_cast<const f32x4*>(xp));
    f32x4 s1 = __builtin_nontemporal_load(reinterpret_cast<const f32x4*>(xp + 4));

    for (int ks = 0; ks < 8; ++ks) {
        bf16x8 sb;
        sb[0] = (__bf16)s0.x; sb[1] = (__bf16)s0.y;
        sb[2] = (__bf16)s0.z; sb[3] = (__bf16)s0.w;
        sb[4] = (__bf16)s1.x; sb[5] = (__bf16)s1.y;
        sb[6] = (__bf16)s1.z; sb[7] = (__bf16)s1.w;
        *reinterpret_cast<bf16x8*>(wr) = sb;       // ds_write_b128
        __syncthreads();

        if (ks < 7) {                              // prefetch next slice -> regs
            s0 = __builtin_nontemporal_load(
                reinterpret_cast<const f32x4*>(xp + (ks + 1) * 32));
            s1 = __builtin_nontemporal_load(
                reinterpret_cast<const f32x4*>(xp + (ks + 1) * 32 + 4));
        }

        const bf16x8 af = *reinterpret_cast<const bf16x8*>(rd);  // ds_read_b128
#pragma unroll
        for (int nf = 0; nf < 16; ++nf) {
            const bf16x8 bfr = wf[(ks * 16 + nf) * 64 + lane];
            acc[nf] = __builtin_amdgcn_mfma_f32_16x16x32_bf16(af, bfr, acc[nf], 0, 0, 0);
        }
        __syncthreads();
    }

    // Epilogue: lane (hi=lane>>4, ccol=lane&15) holds acc[nf][r] =
    // C[row0+wv*16+hi*4+r][nf*16+ccol]. Per-row absmax -> i8, packed 16 B/lane.
    const int hi   = lane >> 4;
    const int ccol = lane & 15;

    float m[4];
#pragma unroll
    for (int r = 0; r < 4; ++r) {
        float mm = 0.f;
#pragma unroll
        for (int nf = 0; nf < 16; ++nf) mm = fmaxf(mm, fabsf(acc[nf][r]));
        m[r] = mm;
    }
#pragma unroll
    for (int w = 1; w < 16; w <<= 1) {
#pragma unroll
        for (int r = 0; r < 4; ++r) m[r] = fmaxf(m[r], __shfl_xor(m[r], w, 64));
    }

#pragma unroll
    for (int r = 0; r < 4; ++r) {
        const int   node = row0 + wv * 16 + hi * 4 + r;
        const float isc  = 127.0f / fmaxf(m[r], 1e-30f);
        uint4 pk = {0u, 0u, 0u, 0u};
        unsigned int* pw = reinterpret_cast<unsigned int*>(&pk);
#pragma unroll
        for (int nf = 0; nf < 16; ++nf) {
            const int q = (int)rintf(acc[nf][r] * isc);
            pw[nf >> 2] |= ((unsigned int)(q & 0xff)) << ((nf & 3) * 8);
        }
        *reinterpret_cast<uint4*>(tab + (size_t)node * 256 + ccol * 16) = pk;
        if (ccol == 0) scales[node] = m[r] * (1.0f / 127.0f);
    }
}

// ---- CSR row pointers from sorted edge_row (int32) ----
__global__ void build_rowptr(const int* __restrict__ erow,
                             int* __restrict__ rowptr) {
    int e = blockIdx.x * blockDim.x + threadIdx.x;
    if (e >= NE) return;
    int r    = erow[e];
    int prev = (e == 0) ? -1 : erow[e - 1];
    for (int q = prev + 1; q <= r; ++q) rowptr[q] = e;
    if (e == NE - 1) {
        for (int q = r + 1; q <= NN; ++q) rowptr[q] = NE;
    }
}

// ---- spmm (i8 permuted table): one wave per row; 4 B/lane = 256 B/edge ----
__global__ __launch_bounds__(256) void spmm_i8(const unsigned int* __restrict__ tab32,
                                               const int* __restrict__ rowptr,
                                               const int* __restrict__ ecol,
                                               const float* __restrict__ eval,
                                               const float* __restrict__ scales,
                                               const float* __restrict__ bias_p,
                                               float* __restrict__ out) {
    const int wave = threadIdx.x >> 6;
    const int lane = threadIdx.x & 63;
    const int row  = blockIdx.x * 4 + wave;

    const int s = rowptr[row];
    const int e = rowptr[row + 1];

    float a0 = 0.f, a1 = 0.f, a2 = 0.f, a3 = 0.f;

#pragma unroll 4
    for (int i = s; i < e; ++i) {
        const int   c = ecol[i];                        // wave-uniform
        const float v = eval[i] * scales[c];            // scales: 400 KB, L2-hot
        const unsigned int g = tab32[((unsigned)c << 6) + lane];  // 32-bit index
        a0 = fmaf(v, (float)(int)(signed char)(g      ), a0);
        a1 = fmaf(v, (float)(int)(signed char)(g >> 8 ), a1);
        a2 = fmaf(v, (float)(int)(signed char)(g >> 16), a2);
        a3 = fmaf(v, (float)(int)(signed char)(g >> 24), a3);
    }

    // lane's features: F(b) = (lane&3)*64 + 16b + (lane>>2); bias pre-permuted
    const f32x4 bp = *reinterpret_cast<const f32x4*>(bias_p + lane * 4);
    float* op = out + (size_t)row * NF + (lane & 3) * 64 + (lane >> 2);
    __builtin_nontemporal_store(a0 + bp.x, op);
    __builtin_nontemporal_store(a1 + bp.y, op + 16);
    __builtin_nontemporal_store(a2 + bp.z, op + 32);
    __builtin_nontemporal_store(a3 + bp.w, op + 48);
}

extern "C" void kernel_launch(void* const* d_in, const int* in_sizes, int n_in,
                              void* d_out, int out_size, void* d_ws, size_t ws_size,
                              hipStream_t stream) {
    const float* x    = (const float*)d_in[0];
    const int*   erow = (const int*)d_in[1];
    const int*   ecol = (const int*)d_in[2];
    const float* eval = (const float*)d_in[3];
    const float* w    = (const float*)d_in[4];
    const float* bias = (const float*)d_in[5];
    float*       out  = (float*)d_out;

    unsigned char* tab    = (unsigned char*)d_ws;                      // 25,600,000 B
    int*           rowptr = (int*)((char*)d_ws + 25600000);            //    400,004 B
    __bf16*        wfrag  = (__bf16*)((char*)d_ws + 26000016);         //    131,072 B
    float*         scales = (float*)((char*)d_ws + 26131088);          //    400,000 B
    float*         bias_p = (float*)((char*)d_ws + 26531088);          //      1,024 B

    prep_w<<<33, 256, 0, stream>>>(w, wfrag, bias, bias_p);
    build_rowptr<<<(NE + 255) / 256, 256, 0, stream>>>(erow, rowptr);
    gemm_q<<<NN / 80, 320, 0, stream>>>(x, wfrag, tab, scales);
    spmm_i8<<<NN / 4, 256, 0, stream>>>(
        reinterpret_cast<const unsigned int*>(tab), rowptr, ecol, eval, scales,
        bias_p, out);
}